// Round 9
// baseline (914.132 us; speedup 1.0000x reference)
//
#include <hip/hip_runtime.h>

// Problem constants (match reference).
#define BB 32
#define MM 2048
#define NN 2048
#define ROWS 64          // rows of A per block
#define CHUNKS (MM / ROWS)   // 32 blocks per batch
#define THREADS 256      // 4 waves; wave w owns rows 16w..16w+15 of the tile

typedef float f32x4 __attribute__((ext_vector_type(4)));

// ws layout (floats), all written-before-read (no zeroing needed):
//   [0, P0)           : At_lambda partials, [slot][col]   (8 MB)
//   [P0, P0+2048)     : per-fused-block {pr, cm} pairs (1024 slots)
//   [P1, P1+512)      : per-finalize-block {stat, dual} pairs (256)
#define P0 ((size_t)BB * CHUNKS * NN)
#define P1 (P0 + 2 * BB * CHUNKS)
#define FIN_BLOCKS 256

__device__ __forceinline__ float waveReduceSum(float v) {
#pragma unroll
    for (int off = 32; off > 0; off >>= 1)
        v += __shfl_down(v, off, 64);
    return v;  // valid in lane 0
}

// fused_main R9: copy-style BURST reads.
// Evidence: read BW pinned at 1.8-1.95 TB/s across 9 configs (prefetch
// depth 0/1/2, nt/cached, 16/32 waves/CU, stagger, interleave) while write
// streams hit 6.4 TB/s. m13's "6.3 TB/s" is a COPY (R+W) -> pure-read
// achievable ~3.2 TB/s. Last untested structural delta vs a copy reader:
// burst issue + wave-contiguous span. Here each wave owns 16 contiguous
// rows (128 KB) and reads each 8 KB row as 8 independent back-to-back
// dwordx4 (8 KB in flight per wave, issue bursts of 8). x lives in LDS to
// keep VGPRs ~112 (c[8]+n[8]+at[8] = 96 data regs) at the (256,4) cap.
__global__ __launch_bounds__(THREADS, 4) void fused_main(
    const float* __restrict__ x_hat, const float* __restrict__ lam_hat,
    const float* __restrict__ A, const float* __restrict__ b_pad,
    float* __restrict__ ws) {
    // Bijective XCD swizzle of the 1024-block grid (1024 % 8 == 0).
    const int lin = blockIdx.y * CHUNKS + blockIdx.x;
    const int swz = (lin & 7) * 128 + (lin >> 3);
    const int b = swz >> 5;          // batch
    const int chunk = swz & 31;      // row-chunk within batch
    const int m0 = chunk * ROWS;
    const int t = threadIdx.x;
    const int w = t >> 6;            // wave 0..3
    const int l = t & 63;            // lane

    __shared__ __align__(16) f32x4 xS[512];    // full x row (8 KB)
    __shared__ __align__(16) f32x4 atS[512];   // At_lambda combine (8 KB)
    __shared__ float lamS[ROWS];
    __shared__ float wp[ROWS];

    const f32x4* xv = (const f32x4*)(x_hat + (size_t)b * NN);
    xS[t] = xv[t];
    xS[256 + t] = xv[256 + t];
    if (t < ROWS) lamS[t] = lam_hat[b * MM + m0 + t];
    __syncthreads();

    const int RV = NN / 4;  // 512 f32x4 per row
    // This wave's 16-row slab.
    const f32x4* Aw = (const f32x4*)(A + ((size_t)b * MM + (size_t)(m0 + 16 * w)) * NN);

    f32x4 at0 = (f32x4)(0.f), at1 = (f32x4)(0.f), at2 = (f32x4)(0.f),
          at3 = (f32x4)(0.f), at4 = (f32x4)(0.f), at5 = (f32x4)(0.f),
          at6 = (f32x4)(0.f), at7 = (f32x4)(0.f);

    f32x4 c0, c1, c2, c3, c4, c5, c6, c7;
    f32x4 n0, n1, n2, n3, n4, n5, n6, n7;

#define LOAD8(p, v)                                                       \
    do {                                                                  \
        v##0 = (p)[l];       v##1 = (p)[l + 64];  v##2 = (p)[l + 128];    \
        v##3 = (p)[l + 192]; v##4 = (p)[l + 256]; v##5 = (p)[l + 320];    \
        v##6 = (p)[l + 384]; v##7 = (p)[l + 448];                         \
    } while (0)

#define BODY(v, RL)                                                       \
    do {                                                                  \
        const float lm = lamS[16 * w + (RL)];                             \
        f32x4 d = v##0 * xS[l];                                           \
        d += v##1 * xS[l + 64];  d += v##2 * xS[l + 128];                 \
        d += v##3 * xS[l + 192]; d += v##4 * xS[l + 256];                 \
        d += v##5 * xS[l + 320]; d += v##6 * xS[l + 384];                 \
        d += v##7 * xS[l + 448];                                          \
        at0 += v##0 * lm; at1 += v##1 * lm; at2 += v##2 * lm;             \
        at3 += v##3 * lm; at4 += v##4 * lm; at5 += v##5 * lm;             \
        at6 += v##6 * lm; at7 += v##7 * lm;                               \
        float dot = (d.x + d.y) + (d.z + d.w);                            \
        dot = waveReduceSum(dot);                                         \
        if (l == 0) wp[16 * w + (RL)] = dot;                              \
    } while (0)

#define ROT8()                                                            \
    do {                                                                  \
        c0 = n0; c1 = n1; c2 = n2; c3 = n3;                               \
        c4 = n4; c5 = n5; c6 = n6; c7 = n7;                               \
    } while (0)

    LOAD8(Aw, c);  // row 0 of the slab in flight (8 independent loads)
    for (int rl = 0; rl < 15; ++rl) {
        const f32x4* np = Aw + (size_t)(rl + 1) * RV;
        LOAD8(np, n);          // burst-issue next row before consuming current
        BODY(c, rl);
        ROT8();
    }
    BODY(c, 15);  // peeled last row
#undef LOAD8
#undef BODY
#undef ROT8
    __syncthreads();

    // Cross-wave At_lambda combine: 4 gated RMW rounds into atS.
#define ATSTORE(op)                                                       \
    do {                                                                  \
        atS[l]       op at0; atS[l + 64]  op at1;                         \
        atS[l + 128] op at2; atS[l + 192] op at3;                         \
        atS[l + 256] op at4; atS[l + 320] op at5;                         \
        atS[l + 384] op at6; atS[l + 448] op at7;                         \
    } while (0)
    if (w == 0) ATSTORE(=);
    __syncthreads();
    if (w == 1) ATSTORE(+=);
    __syncthreads();
    if (w == 2) ATSTORE(+=);
    __syncthreads();
    if (w == 3) ATSTORE(+=);
    __syncthreads();
#undef ATSTORE

    // pr/cm finalize (wave 0, one row per lane).
    if (t < 64) {
        float y = wp[t] - b_pad[b * MM + m0 + t];
        float lm = lamS[t];
        float ry = fmaxf(y, 0.f);
        float pr = ry * ry;
        float c = lm * y;
        float cm = c * c;
        pr = waveReduceSum(pr);
        cm = waveReduceSum(cm);
        if (t == 0) {
            float* prcm = ws + P0 + ((size_t)b * CHUNKS + chunk) * 2;
            prcm[0] = pr;
            prcm[1] = cm;
        }
    }

    // Flush combined At_lambda partial slice (coalesced).
    f32x4* dst = (f32x4*)(ws + ((size_t)b * CHUNKS + chunk) * NN);
    dst[t] = atS[t];
    dst[256 + t] = atS[256 + t];
}

// finalize_partial (R6 version): 256 blocks (1/CU). Block = (b, colgroup of
// 256 floats). Thread = (colvec c in [0,64), k-quarter kq in [0,4)): 8
// independent f32x4 loads, LDS combine of the 4 k-quarters, vectorized dual.
__global__ __launch_bounds__(256) void finalize_partial(
    const float* __restrict__ ws_ro, const float* __restrict__ c_pad,
    const float* __restrict__ lam_hat, float* __restrict__ ws) {
    const int t = threadIdx.x;
    const int b = blockIdx.x >> 3;        // 32 batches
    const int g = blockIdx.x & 7;         // 8 col-groups of 256 floats
    const int c = t & 63;                 // f32x4 colvec within group
    const int kq = t >> 6;                // k-quarter (0..3)

    const f32x4* base = (const f32x4*)ws_ro +
        ((size_t)b * CHUNKS + (size_t)kq * 8) * (NN / 4) + (size_t)g * 64 + c;
    f32x4 s = (f32x4)(0.f);
#pragma unroll
    for (int k = 0; k < 8; ++k) s += base[(size_t)k * (NN / 4)];

    __shared__ __align__(16) f32x4 part[4][64];
    part[kq][c] = s;
    __syncthreads();

    float stat = 0.f, dual = 0.f;
    if (t < 64) {
        f32x4 v = part[0][c] + part[1][c] + part[2][c] + part[3][c];
        f32x4 cp = ((const f32x4*)c_pad)[(size_t)b * (NN / 4) + (size_t)g * 64 + c];
        v += cp;
        stat = v.x * v.x + v.y * v.y + v.z * v.z + v.w * v.w;

        f32x4 lv = ((const f32x4*)lam_hat)[(size_t)blockIdx.x * 64 + c];
        float r0 = fmaxf(-lv.x, 0.f), r1 = fmaxf(-lv.y, 0.f);
        float r2 = fmaxf(-lv.z, 0.f), r3 = fmaxf(-lv.w, 0.f);
        dual = r0 * r0 + r1 * r1 + r2 * r2 + r3 * r3;

        stat = waveReduceSum(stat);
        dual = waveReduceSum(dual);
        if (t == 0) {
            ws[P1 + (size_t)blockIdx.x * 2 + 0] = stat;
            ws[P1 + (size_t)blockIdx.x * 2 + 1] = dual;
        }
    }
}

// combine: reduce 256 {stat,dual} pairs (P1) and 1024 {pr,cm} pairs (P0),
// apply loss weights. One block, 4 waves: one category per wave.
__global__ __launch_bounds__(256) void combine_kernel(
    const float* __restrict__ ws_ro, float* __restrict__ out) {
    const int t = threadIdx.x;
    const int wave = t >> 6;   // 0=stat 1=dual 2=pr 3=cm
    const int lane = t & 63;
    float v = 0.f;
    if (wave == 0) {
#pragma unroll
        for (int j = 0; j < 4; ++j)
            v += ws_ro[P1 + (size_t)((lane << 2) | j) * 2 + 0];
    } else if (wave == 1) {
#pragma unroll
        for (int j = 0; j < 4; ++j)
            v += ws_ro[P1 + (size_t)((lane << 2) | j) * 2 + 1];
    } else if (wave == 2) {
#pragma unroll
        for (int j = 0; j < 16; ++j)
            v += ws_ro[P0 + (size_t)((lane << 4) | j) * 2 + 0];
    } else {
#pragma unroll
        for (int j = 0; j < 16; ++j)
            v += ws_ro[P0 + (size_t)((lane << 4) | j) * 2 + 1];
    }
    v = waveReduceSum(v);
    __shared__ float s[4];
    if (lane == 0) s[wave] = v;
    __syncthreads();
    if (t == 0) {
        const float invBM = 1.0f / (float)(BB * MM);
        const float invBN = 1.0f / (float)(BB * NN);
        float stat = s[0] * invBN;
        float dual = s[1] * invBM;
        float primal = s[2] * invBM;
        float comp = s[3] * invBM;
        out[0] = 0.1f * primal + 0.1f * dual + 0.6f * stat + 0.2f * comp;
    }
}

extern "C" void kernel_launch(void* const* d_in, const int* in_sizes, int n_in,
                              void* d_out, int out_size, void* d_ws, size_t ws_size,
                              hipStream_t stream) {
    const float* x_hat   = (const float*)d_in[0];
    const float* lam_hat = (const float*)d_in[1];
    const float* A       = (const float*)d_in[2];
    const float* b_pad   = (const float*)d_in[3];
    const float* c_pad   = (const float*)d_in[4];
    // d_in[5]/d_in[6] (masks) unused by the reference forward.
    float* out = (float*)d_out;
    float* ws = (float*)d_ws;

    dim3 grid(CHUNKS, BB);
    fused_main<<<grid, THREADS, 0, stream>>>(x_hat, lam_hat, A, b_pad, ws);

    finalize_partial<<<FIN_BLOCKS, 256, 0, stream>>>(ws, c_pad, lam_hat, ws);

    combine_kernel<<<1, 256, 0, stream>>>(ws, out);
}

// Round 10
// 663.886 us; speedup vs baseline: 1.3769x; 1.3769x over previous
//
#include <hip/hip_runtime.h>

// Problem constants (match reference).
#define BB 32
#define MM 2048
#define NN 2048
#define ROWS 64      // rows of A per block -> MM/ROWS = 32 chunks per batch
#define CHUNKS (MM / ROWS)
#define THREADS 256  // 4 waves

typedef float f32x4 __attribute__((ext_vector_type(4)));

// ws layout (floats), all written-before-read (no zeroing needed):
//   [0, BB*CHUNKS*NN)                : At_lambda partials, [b][chunk][col]
//   P0 = BB*CHUNKS*NN, +2*BB*CHUNKS  : per-block {pr, cm} sums
//   P1 = P0 + 2*BB*CHUNKS, +FIN*4    : finalize per-block {stat,dual,pr,cm}
#define P0 ((size_t)BB * CHUNKS * NN)
#define P1 (P0 + 2 * BB * CHUNKS)
#define FIN_BLOCKS 128

__device__ __forceinline__ float waveReduceSum(float v) {
#pragma unroll
    for (int off = 32; off > 0; off >>= 1)
        v += __shfl_down(v, off, 64);
    return v;  // valid in lane 0
}

// DPP row_shr add: pure VALU, no DS pipe. After shr 1,2,4,8 the lane with
// (lane&15)==15 holds the sum of its 16-lane group.
template <int CTRL>
__device__ __forceinline__ float dppAdd(float v) {
    int s = __builtin_amdgcn_update_dpp(0, __builtin_bit_cast(int, v),
                                        CTRL, 0xF, 0xF, false);
    return v + __builtin_bit_cast(float, s);
}

__device__ __forceinline__ float group16Reduce(float v) {
    v = dppAdd<0x111>(v);  // row_shr:1
    v = dppAdd<0x112>(v);  // row_shr:2
    v = dppAdd<0x114>(v);  // row_shr:4
    v = dppAdd<0x118>(v);  // row_shr:8
    return v;              // valid in lane (t&15)==15
}

// fused_main: best-measured config (R3, 661.5 us). ROWS=64, 1-deep
// prefetch, nontemporal loads, DPP reduce, (256,4).
// Session evidence (R0-R9): HBM read throughput is pinned at 1.8-1.95 TB/s
// for this kernel under every source-level variation (prefetch depth
// 0/1/2/8, nt/cached, 14-32 waves/CU, stagger, interleave, burst+LDS-x),
// while write streams hit 6.4 TB/s. fused ~= 537 MB / 1.9 TB/s ~= 285 us
// is this chip's empirical read roofline for this access shape.
__global__ __launch_bounds__(THREADS, 4) void fused_main(
    const float* __restrict__ x_hat, const float* __restrict__ lam_hat,
    const float* __restrict__ A, const float* __restrict__ b_pad,
    float* __restrict__ ws) {
    const int b = blockIdx.y;
    const int chunk = blockIdx.x;
    const int m0 = chunk * ROWS;
    const int t = threadIdx.x;

    __shared__ float lamS[ROWS];
    __shared__ __align__(16) float wp[ROWS * 16];

    if (t < ROWS) lamS[t] = lam_hat[b * MM + m0 + t];
    __syncthreads();

    const f32x4* xv = (const f32x4*)(x_hat + (size_t)b * NN);
    const f32x4 x0 = xv[t];
    const f32x4 x1 = xv[256 + t];

    f32x4 at0 = (f32x4)(0.f);
    f32x4 at1 = (f32x4)(0.f);

    const f32x4* Ab = (const f32x4*)(A + ((size_t)b * MM + (size_t)m0) * NN);

    f32x4 a0 = __builtin_nontemporal_load(Ab + t);
    f32x4 a1 = __builtin_nontemporal_load(Ab + 256 + t);

#define ROW_BODY(r)                                              \
    do {                                                         \
        const float lm = lamS[r];                                \
        f32x4 d = a0 * x0 + a1 * x1;                             \
        at0 += a0 * lm;                                          \
        at1 += a1 * lm;                                          \
        float dot = (d.x + d.y) + (d.z + d.w);                   \
        dot = group16Reduce(dot);                                \
        if ((t & 15) == 15) wp[(r) * 16 + (t >> 4)] = dot;       \
    } while (0)

    for (int r = 0; r < ROWS - 1; ++r) {
        const f32x4* np = Ab + (size_t)(r + 1) * (NN / 4);
        f32x4 n0 = __builtin_nontemporal_load(np + t);
        f32x4 n1 = __builtin_nontemporal_load(np + 256 + t);

        ROW_BODY(r);

        a0 = n0;
        a1 = n1;
    }
    ROW_BODY(ROWS - 1);  // peeled: no clamped re-load of the last row
#undef ROW_BODY
    __syncthreads();

    // Wave 0 finalizes: row t sums its 16 group-partials, then wave-wide
    // pr/cm reduce across the 64 rows.
    if (t < 64) {
        const f32x4* wpv = (const f32x4*)wp;
        f32x4 s4 = wpv[t * 4 + 0] + wpv[t * 4 + 1] +
                   wpv[t * 4 + 2] + wpv[t * 4 + 3];
        float y = (s4.x + s4.y) + (s4.z + s4.w) - b_pad[b * MM + m0 + t];
        float lm = lamS[t];
        float ry = fmaxf(y, 0.f);
        float pr = ry * ry;
        float c = lm * y;
        float cm = c * c;
        pr = waveReduceSum(pr);
        cm = waveReduceSum(cm);
        if (t == 0) {
            float* prcm = ws + P0 + ((size_t)b * CHUNKS + chunk) * 2;
            prcm[0] = pr;
            prcm[1] = cm;
        }
    }

    // Private-slice flush of the At_lambda partial (coalesced, no atomics).
    f32x4* dst = (f32x4*)(ws + ((size_t)b * CHUNKS + chunk) * NN);
    dst[t] = at0;
    dst[256 + t] = at1;
}

// Reduce CHUNKS chunk-partials per column -> stat; plus dual and pr/cm partials.
// Writes per-block {stat,dual,pr,cm} to ws[P1 + blockIdx*4 ..].
__global__ __launch_bounds__(256) void finalize_partial(
    const float* __restrict__ ws_ro, const float* __restrict__ c_pad,
    const float* __restrict__ lam_hat, float* __restrict__ ws) {
    int idx = blockIdx.x * blockDim.x + threadIdx.x;
    int stride = gridDim.x * blockDim.x;
    float stat = 0.f, dual = 0.f, pr = 0.f, cm = 0.f;
    for (int i = idx; i < BB * NN; i += stride) {
        int b = i >> 11;          // / NN
        int col = i & (NN - 1);
        const float* p = ws_ro + (size_t)b * CHUNKS * NN + col;
        float s = 0.f;
#pragma unroll
        for (int k = 0; k < CHUNKS; ++k) s += p[(size_t)k * NN];
        float v = s + c_pad[i];
        stat += v * v;
        float l = lam_hat[i];
        float rn = fmaxf(-l, 0.f);
        dual += rn * rn;
    }
    for (int i = idx; i < BB * CHUNKS; i += stride) {
        pr += ws_ro[P0 + 2 * i];
        cm += ws_ro[P0 + 2 * i + 1];
    }
    stat = waveReduceSum(stat);
    dual = waveReduceSum(dual);
    pr = waveReduceSum(pr);
    cm = waveReduceSum(cm);
    __shared__ float s[16];
    int wave = threadIdx.x >> 6, lane = threadIdx.x & 63;
    if (lane == 0) {
        s[wave * 4 + 0] = stat; s[wave * 4 + 1] = dual;
        s[wave * 4 + 2] = pr;   s[wave * 4 + 3] = cm;
    }
    __syncthreads();
    if (threadIdx.x < 4) {
        float v = s[threadIdx.x] + s[4 + threadIdx.x] + s[8 + threadIdx.x] + s[12 + threadIdx.x];
        ws[P1 + (size_t)blockIdx.x * 4 + threadIdx.x] = v;
    }
}

// Reduce FIN_BLOCKS x {stat,dual,pr,cm} and apply loss weights.
__global__ __launch_bounds__(256) void combine_kernel(
    const float* __restrict__ ws_ro, float* __restrict__ out) {
    const int t = threadIdx.x;
    const int wave = t >> 6;   // category: 0=stat 1=dual 2=pr 3=cm
    const int lane = t & 63;
    // FIN_BLOCKS == 128: each lane folds two entries.
    float v = ws_ro[P1 + (size_t)lane * 4 + wave]
            + ws_ro[P1 + (size_t)(64 + lane) * 4 + wave];
    v = waveReduceSum(v);
    __shared__ float s[4];
    if (lane == 0) s[wave] = v;
    __syncthreads();
    if (t == 0) {
        const float invBM = 1.0f / (float)(BB * MM);
        const float invBN = 1.0f / (float)(BB * NN);
        float stat = s[0] * invBN;
        float dual = s[1] * invBM;
        float primal = s[2] * invBM;
        float comp = s[3] * invBM;
        out[0] = 0.1f * primal + 0.1f * dual + 0.6f * stat + 0.2f * comp;
    }
}

extern "C" void kernel_launch(void* const* d_in, const int* in_sizes, int n_in,
                              void* d_out, int out_size, void* d_ws, size_t ws_size,
                              hipStream_t stream) {
    const float* x_hat   = (const float*)d_in[0];
    const float* lam_hat = (const float*)d_in[1];
    const float* A       = (const float*)d_in[2];
    const float* b_pad   = (const float*)d_in[3];
    const float* c_pad   = (const float*)d_in[4];
    // d_in[5]/d_in[6] (masks) unused by the reference forward.
    float* out = (float*)d_out;
    float* ws = (float*)d_ws;

    dim3 grid(CHUNKS, BB);
    fused_main<<<grid, THREADS, 0, stream>>>(x_hat, lam_hat, A, b_pad, ws);

    finalize_partial<<<FIN_BLOCKS, 256, 0, stream>>>(ws, c_pad, lam_hat, ws);

    combine_kernel<<<1, 256, 0, stream>>>(ws, out);
}